// Round 1
// baseline (188.304 us; speedup 1.0000x reference)
//
#include <hip/hip_runtime.h>
#include <math.h>

#define NPTS 40
#define NN   1600
#define WID  128
#define NPAIR 780   // 40*39/2

// stats block layout (float offsets within a stats buffer)
#define ST_D  0
#define ST_R  5120
#define ST_C  10240
#define ST_TR 15360
#define ST_T  15488
#define ST_SIZE 16384

// workspace layout (float offsets)
#define WS_XA    0
#define WS_XAT   204800
#define WS_XB    409600
#define WS_XBT   614400
#define WS_STA   819200
#define WS_STB   835584
#define WS_STC   851968
#define WS_PAIRS 868352
#define WS_TOTAL 869952

static __device__ __forceinline__ float lrelu(float v) {
    return v >= 0.f ? v : 0.01f * v;
}

// ---------------- Layer 0: X0 = S S^T (1 channel), symmetric basis (11 ops) ----------------
__global__ __launch_bounds__(256) void k_layer0(
    const float* __restrict__ S, const float* __restrict__ W0, const float* __restrict__ b0,
    float* __restrict__ X, float* __restrict__ Xt, float* __restrict__ st)
{
    __shared__ float sS[NPTS * 5];
    __shared__ float sX[NN];
    __shared__ float sP[NN];
    __shared__ float sR[NPTS], sC[NPTS], sD[NPTS], sTT[2];
    const int tid = threadIdx.x;
    const int o = blockIdx.x;

    for (int t = tid; t < NPTS * 5; t += 256) sS[t] = S[t];
    __syncthreads();
    for (int p = tid; p < NN; p += 256) {
        int a = p / NPTS, b = p % NPTS;
        float acc = 0.f;
#pragma unroll
        for (int k = 0; k < 5; ++k) acc += sS[a * 5 + k] * sS[b * 5 + k];
        sX[p] = acc;
    }
    __syncthreads();
    if (tid < NPTS) {
        float r = 0.f, c = 0.f;
        for (int j = 0; j < NPTS; ++j) { r += sX[tid * NPTS + j]; c += sX[j * NPTS + tid]; }
        sR[tid] = r; sC[tid] = c; sD[tid] = sX[tid * 41];
    }
    __syncthreads();
    if (tid == 0) {
        float tr = 0.f, T = 0.f;
        for (int a = 0; a < NPTS; ++a) { tr += sD[a]; T += sR[a]; }
        sTT[0] = tr; sTT[1] = T;
    }
    __syncthreads();

    float w[11];
#pragma unroll
    for (int k = 0; k < 11; ++k) w[k] = W0[o * 11 + k];
    const float tr = sTT[0], T = sTT[1];
    // off-diagonal (a!=b), symmetric grouping
    const float cfX = w[6] - w[7] - w[8] + w[10];                    // (X[a,b]+X[b,a])
    const float cfd = w[5] - w[7] - w[8] - w[9] + 2.f * w[10];       // (d[a]+d[b])
    const float cfR = w[7] - w[10];                                  // (R[a]+R[b])
    const float cfC = w[8] - w[10];                                  // (C[a]+C[b])
    const float so  = w[9] * tr + w[10] * (T - tr) + b0[o * 2 + 1];
    // diagonal (a==b)
    const float cdd = w[0] - w[1] - w[2] - w[3] + 2.f * w[4];
    const float cdR = w[1] - w[4];
    const float cdC = w[2] - w[4];
    const float sd  = w[3] * tr + w[4] * (T - tr) + b0[o * 2 + 0];

    for (int p = tid; p < NN; p += 256) {
        int a = p / NPTS, b = p % NPTS;
        float v;
        if (a == b) {
            v = cdd * sD[a] + cdR * sR[a] + cdC * sC[a] + sd;
        } else {
            float xs = sX[p] + sX[b * NPTS + a];
            v = cfX * xs + cfd * (sD[a] + sD[b]) + cfR * (sR[a] + sR[b]) + cfC * (sC[a] + sC[b]) + so;
        }
        sP[p] = lrelu(v);
    }
    __syncthreads();
    for (int p = tid; p < NN; p += 256) {
        X[o * NN + p] = sP[p];
        Xt[o * NN + p] = sP[(p % NPTS) * NPTS + p / NPTS];
    }
    if (tid < NPTS) {
        float r = 0.f, c = 0.f;
        for (int j = 0; j < NPTS; ++j) { r += sP[tid * NPTS + j]; c += sP[j * NPTS + tid]; }
        st[ST_D + o * NPTS + tid] = sP[tid * 41];
        st[ST_R + o * NPTS + tid] = r;
        st[ST_C + o * NPTS + tid] = c;
        sR[tid] = r; sD[tid] = sP[tid * 41];
    }
    __syncthreads();
    if (tid == 0) {
        float t2 = 0.f, T2 = 0.f;
        for (int a = 0; a < NPTS; ++a) { t2 += sD[a]; T2 += sR[a]; }
        st[ST_TR + o] = t2; st[ST_T + o] = T2;
    }
}

// ---------------- Hidden layer: nonsym basis (15 ops), 128->128 channels ----------------
__global__ __launch_bounds__(256) void k_hidden(
    const float* __restrict__ Xin, const float* __restrict__ Xtin,
    const float* __restrict__ stIn,
    const float* __restrict__ Wl, const float* __restrict__ bl,
    float* __restrict__ Xout, float* __restrict__ Xtout, float* __restrict__ stOut)
{
    __shared__ float c1[WID], c2[WID], cda[WID], cdb[WID], cRa[WID], cRb[WID], cCa[WID], cCb[WID];
    __shared__ float cdd[WID], cdR[WID], cdC[WID], soi[WID], sdi[WID];
    __shared__ float va[NPTS], vb[NPTS], vdg[NPTS];
    __shared__ float sP[NN];
    __shared__ float sScal[2]; // [0]=off scalar, [1]=diag scalar
    const int tid = threadIdx.x;
    const int o = blockIdx.x;

    if (tid < WID) {
        const int i = tid;
        const float* wp = Wl + (o * WID + i) * 15;
        float w[15];
#pragma unroll
        for (int k = 0; k < 15; ++k) w[k] = wp[k];
        c1[i]  = w[6] - w[7] - w[12] + w[14];
        c2[i]  = w[8] - w[10] - w[11] + w[14];
        cda[i] = w[5] - w[7] - w[11] - w[13] + 2.f * w[14];
        cdb[i] = w[9] - w[10] - w[12] - w[13] + 2.f * w[14];
        cRa[i] = w[7] - w[14];
        cRb[i] = w[10] - w[14];
        cCa[i] = w[11] - w[14];
        cCb[i] = w[12] - w[14];
        cdd[i] = w[0] - w[1] - w[2] - w[3] + 2.f * w[4];
        cdR[i] = w[1] - w[4];
        cdC[i] = w[2] - w[4];
        const float tri = stIn[ST_TR + i], Ti = stIn[ST_T + i];
        soi[i] = w[13] * tri + w[14] * (Ti - tri);
        sdi[i] = w[3] * tri + w[4] * (Ti - tri);
    }
    __syncthreads();
    if (tid < 120) {
        const int g = tid / NPTS, a = tid % NPTS;
        float acc = 0.f;
        if (g == 0) {
            for (int i = 0; i < WID; ++i)
                acc += cda[i] * stIn[ST_D + i * NPTS + a] + cRa[i] * stIn[ST_R + i * NPTS + a] + cCa[i] * stIn[ST_C + i * NPTS + a];
            va[a] = acc;
        } else if (g == 1) {
            for (int i = 0; i < WID; ++i)
                acc += cdb[i] * stIn[ST_D + i * NPTS + a] + cRb[i] * stIn[ST_R + i * NPTS + a] + cCb[i] * stIn[ST_C + i * NPTS + a];
            vb[a] = acc;
        } else {
            for (int i = 0; i < WID; ++i)
                acc += cdd[i] * stIn[ST_D + i * NPTS + a] + cdR[i] * stIn[ST_R + i * NPTS + a] + cdC[i] * stIn[ST_C + i * NPTS + a];
            vdg[a] = acc;
        }
    } else if (tid == 120) {
        float s = 0.f;
        for (int i = 0; i < WID; ++i) s += soi[i];
        sScal[0] = s + bl[o * 2 + 1];
    } else if (tid == 121) {
        float s = 0.f;
        for (int i = 0; i < WID; ++i) s += sdi[i];
        sScal[1] = s + bl[o * 2 + 0];
    }
    __syncthreads();

    if (tid < NPTS) sP[tid * 41] = lrelu(vdg[tid] + sScal[1]);

    for (int q = tid; q < NPAIR; q += 256) {
        int a = 0, rem = q;
        while (rem >= 39 - a) { rem -= 39 - a; ++a; }
        const int b = a + 1 + rem;
        const int p = a * NPTS + b;
        const int pt = b * NPTS + a;
        float acc1 = 0.f, acc2 = 0.f;
        for (int i = 0; i < WID; ++i) {
            const float xab = Xin[i * NN + p];
            const float xba = Xtin[i * NN + p];
            acc1 += c1[i] * xab + c2[i] * xba;
            acc2 += c1[i] * xba + c2[i] * xab;
        }
        sP[p]  = lrelu(acc1 + va[a] + vb[b] + sScal[0]);
        sP[pt] = lrelu(acc2 + va[b] + vb[a] + sScal[0]);
    }
    __syncthreads();
    for (int p = tid; p < NN; p += 256) {
        Xout[o * NN + p] = sP[p];
        Xtout[o * NN + p] = sP[(p % NPTS) * NPTS + p / NPTS];
    }
    if (tid < NPTS) {
        float r = 0.f, c = 0.f;
        for (int j = 0; j < NPTS; ++j) { r += sP[tid * NPTS + j]; c += sP[j * NPTS + tid]; }
        stOut[ST_D + o * NPTS + tid] = sP[tid * 41];
        stOut[ST_R + o * NPTS + tid] = r;
        stOut[ST_C + o * NPTS + tid] = c;
        va[tid] = r; vb[tid] = sP[tid * 41];
    }
    __syncthreads();
    if (tid == 0) {
        float t2 = 0.f, T2 = 0.f;
        for (int a = 0; a < NPTS; ++a) { t2 += vb[a]; T2 += va[a]; }
        stOut[ST_TR + o] = t2; stOut[ST_T + o] = T2;
    }
}

// ---------------- Pairs layer: transposed symmetric basis (11 ops), 128 -> 1 channel ----------------
__global__ __launch_bounds__(256) void k_pairs(
    const float* __restrict__ X, const float* __restrict__ Xt,
    const float* __restrict__ st,
    const float* __restrict__ Wp, const float* __restrict__ bp,
    float* __restrict__ pairs)
{
    __shared__ float cx[WID], cpa[WID], cpb[WID], cra[WID], crb[WID], cdd[WID], crc[WID];
    __shared__ float soi[WID], sdi[WID];
    __shared__ float pva[NPTS], pvb[NPTS], pdg[NPTS];
    __shared__ float sScal[2];
    const int tid = threadIdx.x;

    if (tid < WID) {
        const int i = tid;
        const float* pw = Wp + i * 11;
        float p[11];
#pragma unroll
        for (int k = 0; k < 11; ++k) p[k] = pw[k];
        cx[i]  = p[6] - p[7] - p[8] + p[10];               // (X[a,b]+X[b,a])
        cpa[i] = p[1] - p[4] - 2.f * p[7] + 2.f * p[10];   // d[a]
        cpb[i] = p[2] - p[4] - 2.f * p[8] + 2.f * p[10];   // d[b]
        cra[i] = p[7] - p[10];                             // (R[a]+C[a])
        crb[i] = p[8] - p[10];                             // (R[b]+C[b])
        cdd[i] = p[0] - p[3] - 2.f * p[5] + 2.f * p[9];    // diag: d[a]
        crc[i] = p[5] - p[9];                              // diag: (R[a]+C[a])
        const float tri = st[ST_TR + i], Ti = st[ST_T + i];
        soi[i] = p[4] * tri + p[10] * (Ti - tri);
        sdi[i] = p[3] * tri + p[9] * (Ti - tri);
    }
    __syncthreads();
    if (tid < 120) {
        const int g = tid / NPTS, a = tid % NPTS;
        float acc = 0.f;
        if (g == 0) {
            for (int i = 0; i < WID; ++i)
                acc += cpa[i] * st[ST_D + i * NPTS + a] + cra[i] * (st[ST_R + i * NPTS + a] + st[ST_C + i * NPTS + a]);
            pva[a] = acc;
        } else if (g == 1) {
            for (int i = 0; i < WID; ++i)
                acc += cpb[i] * st[ST_D + i * NPTS + a] + crb[i] * (st[ST_R + i * NPTS + a] + st[ST_C + i * NPTS + a]);
            pvb[a] = acc;
        } else {
            for (int i = 0; i < WID; ++i)
                acc += cdd[i] * st[ST_D + i * NPTS + a] + crc[i] * (st[ST_R + i * NPTS + a] + st[ST_C + i * NPTS + a]);
            pdg[a] = acc;
        }
    } else if (tid == 120) {
        float s = 0.f;
        for (int i = 0; i < WID; ++i) s += soi[i];
        sScal[0] = s + bp[1];
    } else if (tid == 121) {
        float s = 0.f;
        for (int i = 0; i < WID; ++i) s += sdi[i];
        sScal[1] = s + bp[0];
    }
    __syncthreads();

    if (blockIdx.x == 0 && tid < NPTS) pairs[tid * 41] = pdg[tid] + sScal[1];

    for (int q = blockIdx.x * 256 + tid; q < NPAIR; q += gridDim.x * 256) {
        int a = 0, rem = q;
        while (rem >= 39 - a) { rem -= 39 - a; ++a; }
        const int b = a + 1 + rem;
        const int p = a * NPTS + b;
        const int pt = b * NPTS + a;
        float acc = 0.f;
        for (int i = 0; i < WID; ++i) acc += cx[i] * (X[i * NN + p] + Xt[i * NN + p]);
        pairs[p]  = acc + pva[a] + pvb[b] + sScal[0];
        pairs[pt] = acc + pva[b] + pvb[a] + sScal[0];
    }
}

// ---------------- Final: A = S^T pairs S + c I (lower-mirror), Jacobi eigensolve, out = S u ----------------
__global__ __launch_bounds__(256) void k_final(
    const float* __restrict__ S, const float* __restrict__ pairs,
    const float* __restrict__ st, const float* __restrict__ Wi,
    const float* __restrict__ bi, float* __restrict__ out)
{
    __shared__ float sS[NPTS * 5];
    __shared__ float sPr[NN];
    __shared__ float M1[5][NPTS];
    __shared__ float sA[25];
    __shared__ float sIsc;
    __shared__ double sU[5];
    const int tid = threadIdx.x;

    for (int t = tid; t < NPTS * 5; t += 256) sS[t] = S[t];
    for (int p = tid; p < NN; p += 256) sPr[p] = pairs[p];
    __syncthreads();

    if (tid < 200) {
        const int c = tid / NPTS, b = tid % NPTS;
        float acc = 0.f;
        for (int a = 0; a < NPTS; ++a) acc += sS[a * 5 + c] * sPr[a * NPTS + b];
        M1[c][b] = acc;
    }
    if (tid == 255) {
        float s = 0.f;
        for (int i = 0; i < WID; ++i) {
            const float tri = st[ST_TR + i], Ti = st[ST_T + i];
            s += Wi[i * 2 + 0] * tri + Wi[i * 2 + 1] * (Ti - tri);
        }
        sIsc = s + bi[0];
    }
    __syncthreads();
    if (tid < 25) {
        const int c = tid / 5, d = tid % 5;
        float acc = 0.f;
        for (int b = 0; b < NPTS; ++b) acc += M1[c][b] * sS[b * 5 + d];
        sA[tid] = acc;
    }
    __syncthreads();

    if (tid == 0) {
        double A[5][5], V[5][5];
        // numpy eigh semantics: use lower triangle of A
        for (int c = 0; c < 5; ++c)
            for (int d = 0; d < 5; ++d)
                A[c][d] = (double)((c >= d) ? sA[c * 5 + d] : sA[d * 5 + c]);
        for (int c = 0; c < 5; ++c) A[c][c] += (double)sIsc;
        for (int c = 0; c < 5; ++c)
            for (int d = 0; d < 5; ++d) V[c][d] = (c == d) ? 1.0 : 0.0;

        double dscale = 1.0;
        for (int c = 0; c < 5; ++c) dscale += A[c][c] * A[c][c];
        for (int sweep = 0; sweep < 30; ++sweep) {
            double off = 0.0;
            for (int p = 0; p < 4; ++p)
                for (int q = p + 1; q < 5; ++q) off += A[p][q] * A[p][q];
            if (off < 1e-26 * dscale) break;
            for (int p = 0; p < 4; ++p) {
                for (int q = p + 1; q < 5; ++q) {
                    const double apq = A[p][q];
                    if (fabs(apq) < 1e-300) continue;
                    const double theta = (A[q][q] - A[p][p]) / (2.0 * apq);
                    const double t = (theta >= 0.0 ? 1.0 : -1.0) / (fabs(theta) + sqrt(theta * theta + 1.0));
                    const double c = 1.0 / sqrt(t * t + 1.0);
                    const double s = t * c;
                    for (int k = 0; k < 5; ++k) {
                        const double akp = A[k][p], akq = A[k][q];
                        A[k][p] = c * akp - s * akq;
                        A[k][q] = s * akp + c * akq;
                    }
                    for (int k = 0; k < 5; ++k) {
                        const double apk = A[p][k], aqk = A[q][k];
                        A[p][k] = c * apk - s * aqk;
                        A[q][k] = s * apk + c * aqk;
                    }
                    for (int k = 0; k < 5; ++k) {
                        const double vkp = V[k][p], vkq = V[k][q];
                        V[k][p] = c * vkp - s * vkq;
                        V[k][q] = s * vkp + c * vkq;
                    }
                }
            }
        }
        int best = 0;
        for (int k = 1; k < 5; ++k) if (A[k][k] > A[best][best]) best = k;
        double u[5];
        for (int k = 0; k < 5; ++k) u[k] = V[k][best];
        // sign convention attempt #1: largest-|component| positive
        int jm = 0; double am = fabs(u[0]);
        for (int k = 1; k < 5; ++k) if (fabs(u[k]) > am) { am = fabs(u[k]); jm = k; }
        if (u[jm] < 0.0) for (int k = 0; k < 5; ++k) u[k] = -u[k];
        for (int k = 0; k < 5; ++k) sU[k] = u[k];
    }
    __syncthreads();
    if (tid < NPTS) {
        float acc = 0.f;
#pragma unroll
        for (int k = 0; k < 5; ++k) acc += sS[tid * 5 + k] * (float)sU[k];
        out[tid] = acc;
    }
}

extern "C" void kernel_launch(void* const* d_in, const int* in_sizes, int n_in,
                              void* d_out, int out_size, void* d_ws, size_t ws_size,
                              hipStream_t stream) {
    const float* S  = (const float*)d_in[0];
    // d_in[1] basis_sym_nonsym, d_in[2] basis_nonsym, d_in[3] bias_basis: unused (structure derived analytically)
    const float* W0 = (const float*)d_in[4];
    const float* b0 = (const float*)d_in[5];
    const float* Wh = (const float*)d_in[6];
    const float* bh = (const float*)d_in[7];
    const float* Wp = (const float*)d_in[8];
    const float* bp = (const float*)d_in[9];
    const float* Wi = (const float*)d_in[10];
    const float* bi = (const float*)d_in[11];
    float* out = (float*)d_out;
    float* ws = (float*)d_ws;
    if (ws_size < (size_t)WS_TOTAL * sizeof(float)) return; // workspace too small: fail visibly

    k_layer0<<<WID, 256, 0, stream>>>(S, W0, b0, ws + WS_XA, ws + WS_XAT, ws + WS_STA);
    k_hidden<<<WID, 256, 0, stream>>>(ws + WS_XA, ws + WS_XAT, ws + WS_STA,
                                      Wh, bh, ws + WS_XB, ws + WS_XBT, ws + WS_STB);
    k_hidden<<<WID, 256, 0, stream>>>(ws + WS_XB, ws + WS_XBT, ws + WS_STB,
                                      Wh + WID * WID * 15, bh + WID * 2,
                                      ws + WS_XA, ws + WS_XAT, ws + WS_STC);
    k_pairs<<<4, 256, 0, stream>>>(ws + WS_XA, ws + WS_XAT, ws + WS_STC, Wp, bp, ws + WS_PAIRS);
    k_final<<<1, 256, 0, stream>>>(S, ws + WS_PAIRS, ws + WS_STC, Wi, bi, out);
}

// Round 2
// 134.032 us; speedup vs baseline: 1.4049x; 1.4049x over previous
//
#include <hip/hip_runtime.h>
#include <math.h>

#define NPTS 40
#define NN   1600
#define WID  128
#define NPAIR 780   // 40*39/2

// stats block layout (float offsets): D/R/C indexed [i*40+a]
#define ST_D  0
#define ST_R  5120
#define ST_C  10240
#define ST_TR 15360
#define ST_T  15488
#define ST_SIZE 16384

// vterm block layout (hidden layers): va/vb/vdg indexed [a*128+o]
#define VT_VA   0
#define VT_VB   5120
#define VT_VDG  10240
#define VT_SOFF 15360
#define VT_SDG  15488
#define VT_SIZE 15616

// pairs-layer vterm layout
#define PVA 0
#define PVB 40
#define PDG 80
#define PSOFF 120
#define PSDG 121

// coefficient matrices per hidden layer: 15 mats of [i*128+o]
#define CM_SZ1 16384
#define CM_SIZE (15*16384)

// workspace layout (float offsets)
#define WS_XTA   0
#define WS_XTB   204800
#define WS_STA   409600
#define WS_STB   425984
#define WS_STC   442368
#define WS_CM0   458752
#define WS_CM1   704512
#define WS_VT1   950272
#define WS_VT2   965888
#define WS_VTP   981504
#define WS_PRAW  981632
#define WS_TOTAL 983232

static __device__ __forceinline__ float lrelu(float v) {
    return v >= 0.f ? v : 0.01f * v;
}

// decode pair index q -> (a,b), a<b
static __device__ __forceinline__ void pair_decode(int q, int& a, int& b) {
    int aa = 0, rem = q;
    while (rem >= 39 - aa) { rem -= 39 - aa; ++aa; }
    a = aa; b = aa + 1 + rem;
}

// ---------------- Kernel 1: layer0 (per-o block) + weight coef precompute ----------------
__global__ __launch_bounds__(256) void k_l0c(
    const float* __restrict__ S, const float* __restrict__ W0, const float* __restrict__ b0,
    const float* __restrict__ Wh,
    float* __restrict__ XT, float* __restrict__ st,
    float* __restrict__ cm0, float* __restrict__ cm1)
{
    const int tid = threadIdx.x;
    const int o = blockIdx.x;

    // ---- coefficient precompute: one (l, oo, ii) per thread, 128*256 = 32768 total ----
    {
        const int idx = blockIdx.x * 256 + tid;       // 0..32767
        const int l = idx >> 14;
        const int r2 = idx & 16383;
        const int oo = r2 >> 7;                        // out channel
        const int ii = r2 & 127;                       // in channel
        const float* w = Wh + ((l * WID + oo) * WID + ii) * 15;
        float* cm = l ? cm1 : cm0;
        const int base = ii * 128 + oo;
        const float w0=w[0],w1=w[1],w2=w[2],w3=w[3],w4=w[4],w5=w[5],w6=w[6],w7=w[7],
                    w8=w[8],w9=w[9],w10=w[10],w11=w[11],w12=w[12],w13=w[13],w14=w[14];
        cm[ 0*CM_SZ1+base] = w6 - w7 - w12 + w14;                     // c1 (xab)
        cm[ 1*CM_SZ1+base] = w8 - w10 - w11 + w14;                    // c2 (xba)
        cm[ 2*CM_SZ1+base] = w5 - w7 - w11 - w13 + 2.f*w14;           // cda
        cm[ 3*CM_SZ1+base] = w9 - w10 - w12 - w13 + 2.f*w14;          // cdb
        cm[ 4*CM_SZ1+base] = w7 - w14;                                // cRa
        cm[ 5*CM_SZ1+base] = w10 - w14;                               // cRb
        cm[ 6*CM_SZ1+base] = w11 - w14;                               // cCa
        cm[ 7*CM_SZ1+base] = w12 - w14;                               // cCb
        cm[ 8*CM_SZ1+base] = w0 - w1 - w2 - w3 + 2.f*w4;              // cdd
        cm[ 9*CM_SZ1+base] = w1 - w4;                                 // cdR
        cm[10*CM_SZ1+base] = w2 - w4;                                 // cdC
        cm[11*CM_SZ1+base] = w13 - w14;                               // mtr_off
        cm[12*CM_SZ1+base] = w14;                                     // mT_off
        cm[13*CM_SZ1+base] = w3 - w4;                                 // mtr_dg
        cm[14*CM_SZ1+base] = w4;                                      // mT_dg
    }

    // ---- layer 0 (symmetric basis, 11 ops) — same math as validated round 1 ----
    __shared__ float sS[NPTS * 5];
    __shared__ float sX[NN];
    __shared__ float sP[NN];
    __shared__ float sR[NPTS], sC[NPTS], sD[NPTS], sTT[2];

    for (int t = tid; t < NPTS * 5; t += 256) sS[t] = S[t];
    __syncthreads();
    for (int p = tid; p < NN; p += 256) {
        int a = p / NPTS, b = p % NPTS;
        float acc = 0.f;
#pragma unroll
        for (int k = 0; k < 5; ++k) acc += sS[a * 5 + k] * sS[b * 5 + k];
        sX[p] = acc;
    }
    __syncthreads();
    if (tid < NPTS) {
        float r = 0.f, c = 0.f;
        for (int j = 0; j < NPTS; ++j) { r += sX[tid * NPTS + j]; c += sX[j * NPTS + tid]; }
        sR[tid] = r; sC[tid] = c; sD[tid] = sX[tid * 41];
    }
    __syncthreads();
    if (tid == 0) {
        float tr = 0.f, T = 0.f;
        for (int a = 0; a < NPTS; ++a) { tr += sD[a]; T += sR[a]; }
        sTT[0] = tr; sTT[1] = T;
    }
    __syncthreads();

    float w[11];
#pragma unroll
    for (int k = 0; k < 11; ++k) w[k] = W0[o * 11 + k];
    const float tr = sTT[0], T = sTT[1];
    const float cfX = w[6] - w[7] - w[8] + w[10];
    const float cfd = w[5] - w[7] - w[8] - w[9] + 2.f * w[10];
    const float cfR = w[7] - w[10];
    const float cfC = w[8] - w[10];
    const float so  = w[9] * tr + w[10] * (T - tr) + b0[o * 2 + 1];
    const float cdd = w[0] - w[1] - w[2] - w[3] + 2.f * w[4];
    const float cdR = w[1] - w[4];
    const float cdC = w[2] - w[4];
    const float sd  = w[3] * tr + w[4] * (T - tr) + b0[o * 2 + 0];

    for (int p = tid; p < NN; p += 256) {
        int a = p / NPTS, b = p % NPTS;
        float v;
        if (a == b) {
            v = cdd * sD[a] + cdR * sR[a] + cdC * sC[a] + sd;
        } else {
            float xs = sX[p] + sX[b * NPTS + a];
            v = cfX * xs + cfd * (sD[a] + sD[b]) + cfR * (sR[a] + sR[b]) + cfC * (sC[a] + sC[b]) + so;
        }
        sP[p] = lrelu(v);
    }
    __syncthreads();
    // write transposed layout XT[p][o]
    for (int p = tid; p < NN; p += 256) XT[p * WID + o] = sP[p];
    // stats of layer-0 output (this channel o)
    if (tid < NPTS) {
        float r = 0.f, c = 0.f;
        for (int j = 0; j < NPTS; ++j) { r += sP[tid * NPTS + j]; c += sP[j * NPTS + tid]; }
        st[ST_D + o * NPTS + tid] = sP[tid * 41];
        st[ST_R + o * NPTS + tid] = r;
        st[ST_C + o * NPTS + tid] = c;
        sR[tid] = r; sD[tid] = sP[tid * 41];
    }
    __syncthreads();
    if (tid == 0) {
        float t2 = 0.f, T2 = 0.f;
        for (int a = 0; a < NPTS; ++a) { t2 += sD[a]; T2 += sR[a]; }
        st[ST_TR + o] = t2; st[ST_T + o] = T2;
    }
}

// ---------------- k_sv: stats (optional) + vterm contraction for one hidden layer ----------------
// grid 41: blocks 0..39 = per-a vterms (va, vb, vdg); block 40 = scal terms.
template<bool COMP>
__global__ __launch_bounds__(256) void k_sv(
    const float* __restrict__ XT, const float* __restrict__ stIn,
    float* __restrict__ stOut,
    const float* __restrict__ cm, const float* __restrict__ bias,
    float* __restrict__ vt)
{
    const int tid = threadIdx.x;
    const int i = tid & 127, h = tid >> 7;
    const int a = blockIdx.x;
    __shared__ float sD[128], sR[128], sC[128], sTr[128], sT[128];
    __shared__ float part[2][2][128];
    __shared__ float vpart[3][2][128];

    if (a < 40) {
        if (COMP) {
            float r = 0.f, c = 0.f;
            for (int b = h * 20; b < h * 20 + 20; ++b) {
                r += XT[(a * 40 + b) * WID + i];
                c += XT[(b * 40 + a) * WID + i];
            }
            part[0][h][i] = r; part[1][h][i] = c;
            __syncthreads();
            if (tid < 128) {
                sR[i] = part[0][0][i] + part[0][1][i];
                sC[i] = part[1][0][i] + part[1][1][i];
                sD[i] = XT[(a * 41) * WID + i];
                stOut[ST_D + i * 40 + a] = sD[i];
                stOut[ST_R + i * 40 + a] = sR[i];
                stOut[ST_C + i * 40 + a] = sC[i];
            }
        } else {
            if (tid < 128) {
                sD[i] = stIn[ST_D + i * 40 + a];
                sR[i] = stIn[ST_R + i * 40 + a];
                sC[i] = stIn[ST_C + i * 40 + a];
            }
            __syncthreads();  // keep barrier counts uniform within block
        }
        __syncthreads();
        const int o = i;
        float acca = 0.f, accb = 0.f, accg = 0.f;
        for (int k = h * 64; k < h * 64 + 64; ++k) {
            const float d = sD[k], r = sR[k], c = sC[k];
            acca += cm[ 2*CM_SZ1 + k*128 + o] * d + cm[ 4*CM_SZ1 + k*128 + o] * r + cm[ 6*CM_SZ1 + k*128 + o] * c;
            accb += cm[ 3*CM_SZ1 + k*128 + o] * d + cm[ 5*CM_SZ1 + k*128 + o] * r + cm[ 7*CM_SZ1 + k*128 + o] * c;
            accg += cm[ 8*CM_SZ1 + k*128 + o] * d + cm[ 9*CM_SZ1 + k*128 + o] * r + cm[10*CM_SZ1 + k*128 + o] * c;
        }
        vpart[0][h][o] = acca; vpart[1][h][o] = accb; vpart[2][h][o] = accg;
        __syncthreads();
        if (tid < 128) {
            vt[VT_VA  + a * 128 + o] = vpart[0][0][o] + vpart[0][1][o];
            vt[VT_VB  + a * 128 + o] = vpart[1][0][o] + vpart[1][1][o];
            vt[VT_VDG + a * 128 + o] = vpart[2][0][o] + vpart[2][1][o];
        }
    } else {
        if (COMP) {
            float tt = 0.f;
            for (int p = h * 800; p < (h + 1) * 800; ++p) tt += XT[p * WID + i];
            part[0][h][i] = tt;
            __syncthreads();
            if (tid < 128) {
                sT[i] = part[0][0][i] + part[0][1][i];
                float trv = 0.f;
                for (int a2 = 0; a2 < 40; ++a2) trv += XT[(a2 * 41) * WID + i];
                sTr[i] = trv;
                stOut[ST_TR + i] = trv; stOut[ST_T + i] = sT[i];
            }
        } else {
            if (tid < 128) { sTr[i] = stIn[ST_TR + i]; sT[i] = stIn[ST_T + i]; }
            __syncthreads();
        }
        __syncthreads();
        const int o = i;
        float soff = 0.f, sdg = 0.f;
        for (int k = h * 64; k < h * 64 + 64; ++k) {
            const float trv = sTr[k], Tv = sT[k];
            soff += cm[11*CM_SZ1 + k*128 + o] * trv + cm[12*CM_SZ1 + k*128 + o] * Tv;
            sdg  += cm[13*CM_SZ1 + k*128 + o] * trv + cm[14*CM_SZ1 + k*128 + o] * Tv;
        }
        vpart[0][h][o] = soff; vpart[1][h][o] = sdg;
        __syncthreads();
        if (tid < 128) {
            vt[VT_SOFF + o] = vpart[0][0][o] + vpart[0][1][o] + bias[o * 2 + 1];
            vt[VT_SDG  + o] = vpart[1][0][o] + vpart[1][1][o] + bias[o * 2 + 0];
        }
    }
}

// ---------------- k_hid: the 128x256x780 contraction. grid 391 (2 pairs/block + diag block) ----------------
__global__ __launch_bounds__(256) void k_hid(
    const float* __restrict__ XTin, float* __restrict__ XTout,
    const float* __restrict__ cm, const float* __restrict__ vt)
{
    const int tid = threadIdx.x;
    const int blk = blockIdx.x;
    if (blk == 390) { // diagonal
        const int o = tid & 127, h = tid >> 7;
        const float sdg = vt[VT_SDG + o];
        for (int a = h; a < 40; a += 2)
            XTout[(a * 41) * WID + o] = lrelu(vt[VT_VDG + a * 128 + o] + sdg);
        return;
    }
    __shared__ float sxab[2][128], sxba[2][128];
    const int j = tid >> 7, o = tid & 127;
    int aa, bb;
    pair_decode(blk * 2 + j, aa, bb);
    const int p = aa * 40 + bb, pt = bb * 40 + aa;
    sxab[j][o] = XTin[p * WID + o];
    sxba[j][o] = XTin[pt * WID + o];
    __syncthreads();

    float acc1 = 0.f, acc2 = 0.f;
#pragma unroll 8
    for (int i2 = 0; i2 < 128; ++i2) {
        const float c1v = cm[i2 * 128 + o];
        const float c2v = cm[CM_SZ1 + i2 * 128 + o];
        const float xab = sxab[j][i2];
        const float xba = sxba[j][i2];
        acc1 += c1v * xab + c2v * xba;
        acc2 += c1v * xba + c2v * xab;
    }
    const float soff = vt[VT_SOFF + o];
    XTout[p * WID + o]  = lrelu(acc1 + vt[VT_VA + aa * 128 + o] + vt[VT_VB + bb * 128 + o] + soff);
    XTout[pt * WID + o] = lrelu(acc2 + vt[VT_VA + bb * 128 + o] + vt[VT_VB + aa * 128 + o] + soff);
}

// ---------------- k_svp: pairs-layer stats+vterms (blocks 0..40) + raw pair reduction (41..820) ----------------
__global__ __launch_bounds__(256) void k_svp(
    const float* __restrict__ XT, float* __restrict__ stOut,
    const float* __restrict__ Wp, const float* __restrict__ bp,
    float* __restrict__ vtp, float* __restrict__ praw)
{
    const int tid = threadIdx.x;
    const int i = tid & 127, h = tid >> 7;
    const int blk = blockIdx.x;
    __shared__ float sD[128], sR[128], sC[128];
    __shared__ float part[2][2][128];
    __shared__ float red[3][128];

    if (blk < 40) {
        const int a = blk;
        float r = 0.f, c = 0.f;
        for (int b = h * 20; b < h * 20 + 20; ++b) {
            r += XT[(a * 40 + b) * WID + i];
            c += XT[(b * 40 + a) * WID + i];
        }
        part[0][h][i] = r; part[1][h][i] = c;
        __syncthreads();
        if (tid < 128) {
            sR[i] = part[0][0][i] + part[0][1][i];
            sC[i] = part[1][0][i] + part[1][1][i];
            sD[i] = XT[(a * 41) * WID + i];
            stOut[ST_D + i * 40 + a] = sD[i];
            stOut[ST_R + i * 40 + a] = sR[i];
            stOut[ST_C + i * 40 + a] = sC[i];
        }
        __syncthreads();
        if (tid < 128) {
            const float* pw = Wp + i * 11;
            const float p0=pw[0],p1=pw[1],p2=pw[2],p3=pw[3],p4=pw[4],p5=pw[5],
                        p7=pw[7],p8=pw[8],p9=pw[9],p10=pw[10];
            const float cpa = p1 - p4 - 2.f*p7 + 2.f*p10;
            const float cpb = p2 - p4 - 2.f*p8 + 2.f*p10;
            const float cra = p7 - p10;
            const float crb = p8 - p10;
            const float cddp = p0 - p3 - 2.f*p5 + 2.f*p9;
            const float crcp = p5 - p9;
            const float rc = sR[i] + sC[i];
            red[0][i] = cpa * sD[i] + cra * rc;
            red[1][i] = cpb * sD[i] + crb * rc;
            red[2][i] = cddp * sD[i] + crcp * rc;
        }
        __syncthreads();
        for (int s = 64; s > 0; s >>= 1) {
            if (tid < s) {
                red[0][tid] += red[0][tid + s];
                red[1][tid] += red[1][tid + s];
                red[2][tid] += red[2][tid + s];
            }
            __syncthreads();
        }
        if (tid == 0) {
            vtp[PVA + a] = red[0][0];
            vtp[PVB + a] = red[1][0];
            vtp[PDG + a] = red[2][0];
        }
    } else if (blk == 40) {
        float tt = 0.f;
        for (int p = h * 800; p < (h + 1) * 800; ++p) tt += XT[p * WID + i];
        part[0][h][i] = tt;
        __syncthreads();
        if (tid < 128) {
            const float Tv = part[0][0][i] + part[0][1][i];
            float trv = 0.f;
            for (int a2 = 0; a2 < 40; ++a2) trv += XT[(a2 * 41) * WID + i];
            stOut[ST_TR + i] = trv; stOut[ST_T + i] = Tv;
            const float p3 = Wp[i*11+3], p4 = Wp[i*11+4], p9 = Wp[i*11+9], p10 = Wp[i*11+10];
            red[0][i] = (p4 - p10) * trv + p10 * Tv;
            red[1][i] = (p3 - p9) * trv + p9 * Tv;
        }
        __syncthreads();
        for (int s = 64; s > 0; s >>= 1) {
            if (tid < s) { red[0][tid] += red[0][tid + s]; red[1][tid] += red[1][tid + s]; }
            __syncthreads();
        }
        if (tid == 0) {
            vtp[PSOFF] = red[0][0] + bp[1];
            vtp[PSDG]  = red[1][0] + bp[0];
        }
    } else {
        int aa, bb;
        pair_decode(blk - 41, aa, bb);
        const int p = aa * 40 + bb, pt = bb * 40 + aa;
        if (tid < 128) {
            const float p6 = Wp[i*11+6], p7 = Wp[i*11+7], p8 = Wp[i*11+8], p10 = Wp[i*11+10];
            red[0][i] = (p6 - p7 - p8 + p10) * (XT[p * WID + i] + XT[pt * WID + i]);
        }
        __syncthreads();
        for (int s = 64; s > 0; s >>= 1) {
            if (tid < s) red[0][tid] += red[0][tid + s];
            __syncthreads();
        }
        if (tid == 0) { praw[p] = red[0][0]; praw[pt] = red[0][0]; }
    }
}

// ---------------- k_final: assemble pairs, A = S^T pairs S + c I (lower-mirror), Jacobi, out = S u ----------------
__global__ __launch_bounds__(256) void k_final(
    const float* __restrict__ S, const float* __restrict__ praw,
    const float* __restrict__ vtp,
    const float* __restrict__ st, const float* __restrict__ Wi,
    const float* __restrict__ bi, float* __restrict__ out)
{
    __shared__ float sS[NPTS * 5];
    __shared__ float sPr[NN];
    __shared__ float M1[5][NPTS];
    __shared__ float sA[25];
    __shared__ float sIsc;
    __shared__ double sU[5];
    const int tid = threadIdx.x;

    for (int t = tid; t < NPTS * 5; t += 256) sS[t] = S[t];
    for (int p = tid; p < NN; p += 256) {
        const int a = p / NPTS, b = p % NPTS;
        float v;
        if (a == b) v = vtp[PDG + a] + vtp[PSDG];
        else        v = praw[p] + vtp[PVA + a] + vtp[PVB + b] + vtp[PSOFF];
        sPr[p] = v;
    }
    __syncthreads();

    if (tid < 200) {
        const int c = tid / NPTS, b = tid % NPTS;
        float acc = 0.f;
        for (int a = 0; a < NPTS; ++a) acc += sS[a * 5 + c] * sPr[a * NPTS + b];
        M1[c][b] = acc;
    }
    if (tid == 255) {
        float s = 0.f;
        for (int i = 0; i < WID; ++i) {
            const float tri = st[ST_TR + i], Ti = st[ST_T + i];
            s += Wi[i * 2 + 0] * tri + Wi[i * 2 + 1] * (Ti - tri);
        }
        sIsc = s + bi[0];
    }
    __syncthreads();
    if (tid < 25) {
        const int c = tid / 5, d = tid % 5;
        float acc = 0.f;
        for (int b = 0; b < NPTS; ++b) acc += M1[c][b] * sS[b * 5 + d];
        sA[tid] = acc;
    }
    __syncthreads();

    if (tid == 0) {
        double A[5][5], V[5][5];
        for (int c = 0; c < 5; ++c)
            for (int d = 0; d < 5; ++d)
                A[c][d] = (double)((c >= d) ? sA[c * 5 + d] : sA[d * 5 + c]);
        for (int c = 0; c < 5; ++c) A[c][c] += (double)sIsc;
        for (int c = 0; c < 5; ++c)
            for (int d = 0; d < 5; ++d) V[c][d] = (c == d) ? 1.0 : 0.0;

        double dscale = 1.0;
        for (int c = 0; c < 5; ++c) dscale += A[c][c] * A[c][c];
        for (int sweep = 0; sweep < 30; ++sweep) {
            double off = 0.0;
            for (int p = 0; p < 4; ++p)
                for (int q = p + 1; q < 5; ++q) off += A[p][q] * A[p][q];
            if (off < 1e-26 * dscale) break;
            for (int p = 0; p < 4; ++p) {
                for (int q = p + 1; q < 5; ++q) {
                    const double apq = A[p][q];
                    if (fabs(apq) < 1e-300) continue;
                    const double theta = (A[q][q] - A[p][p]) / (2.0 * apq);
                    const double t = (theta >= 0.0 ? 1.0 : -1.0) / (fabs(theta) + sqrt(theta * theta + 1.0));
                    const double c = 1.0 / sqrt(t * t + 1.0);
                    const double s = t * c;
                    for (int k = 0; k < 5; ++k) {
                        const double akp = A[k][p], akq = A[k][q];
                        A[k][p] = c * akp - s * akq;
                        A[k][q] = s * akp + c * akq;
                    }
                    for (int k = 0; k < 5; ++k) {
                        const double apk = A[p][k], aqk = A[q][k];
                        A[p][k] = c * apk - s * aqk;
                        A[q][k] = s * apk + c * aqk;
                    }
                    for (int k = 0; k < 5; ++k) {
                        const double vkp = V[k][p], vkq = V[k][q];
                        V[k][p] = c * vkp - s * vkq;
                        V[k][q] = s * vkp + c * vkq;
                    }
                }
            }
        }
        int best = 0;
        for (int k = 1; k < 5; ++k) if (A[k][k] > A[best][best]) best = k;
        double u[5];
        for (int k = 0; k < 5; ++k) u[k] = V[k][best];
        int jm = 0; double am = fabs(u[0]);
        for (int k = 1; k < 5; ++k) if (fabs(u[k]) > am) { am = fabs(u[k]); jm = k; }
        if (u[jm] < 0.0) for (int k = 0; k < 5; ++k) u[k] = -u[k];
        for (int k = 0; k < 5; ++k) sU[k] = u[k];
    }
    __syncthreads();
    if (tid < NPTS) {
        float acc = 0.f;
#pragma unroll
        for (int k = 0; k < 5; ++k) acc += sS[tid * 5 + k] * (float)sU[k];
        out[tid] = acc;
    }
}

extern "C" void kernel_launch(void* const* d_in, const int* in_sizes, int n_in,
                              void* d_out, int out_size, void* d_ws, size_t ws_size,
                              hipStream_t stream) {
    const float* S  = (const float*)d_in[0];
    // d_in[1..3] basis tensors: unused (structure derived analytically)
    const float* W0 = (const float*)d_in[4];
    const float* b0 = (const float*)d_in[5];
    const float* Wh = (const float*)d_in[6];
    const float* bh = (const float*)d_in[7];
    const float* Wp = (const float*)d_in[8];
    const float* bp = (const float*)d_in[9];
    const float* Wi = (const float*)d_in[10];
    const float* bi = (const float*)d_in[11];
    float* out = (float*)d_out;
    float* ws = (float*)d_ws;
    if (ws_size < (size_t)WS_TOTAL * sizeof(float)) return;

    float* XTA = ws + WS_XTA;
    float* XTB = ws + WS_XTB;
    float* stA = ws + WS_STA;
    float* stB = ws + WS_STB;
    float* stC = ws + WS_STC;
    float* cm0 = ws + WS_CM0;
    float* cm1 = ws + WS_CM1;
    float* vt1 = ws + WS_VT1;
    float* vt2 = ws + WS_VT2;
    float* vtp = ws + WS_VTP;
    float* praw = ws + WS_PRAW;

    k_l0c<<<WID, 256, 0, stream>>>(S, W0, b0, Wh, XTA, stA, cm0, cm1);
    k_sv<false><<<41, 256, 0, stream>>>(XTA, stA, stB, cm0, bh, vt1);
    k_hid<<<391, 256, 0, stream>>>(XTA, XTB, cm0, vt1);
    k_sv<true><<<41, 256, 0, stream>>>(XTB, stB, stB, cm1, bh + 2 * WID, vt2);
    k_hid<<<391, 256, 0, stream>>>(XTB, XTA, cm1, vt2);
    k_svp<<<821, 256, 0, stream>>>(XTA, stC, Wp, bp, vtp, praw);
    k_final<<<1, 256, 0, stream>>>(S, praw, vtp, stC, Wi, bi, out);
}